// Round 9
// baseline (391.024 us; speedup 1.0000x reference)
//
#include <hip/hip_runtime.h>

// B=64, L=256, C_IN=5, KERNEL=4, C=8. 253 steps padded to 256 = 16 chunks x 16.
// ONE kernel, 256 blocks = (batch 64) x (i-pair 4), 1024 thr = 16 waves
// -> 4 waves/SIMD (R8 had 2; issue-eff 45% -> target ~60%).
// wave = chunk (16 serial iters). Template-specialized on iq so the two
// tracked i's are compile-time: R8's redundant u-state (u==t at i0,i1) and
// iq-select chains are gone (~114 -> ~90 instr/iter).
// s4 reduction via conflict-free LDS atomicAdd (one barrier, no ladder).
#define L_IN  256
#define CIN   5
#define SIG_N 4680   // 8 + 64 + 512 + 4096
#define NCH   16     // chunks
#define CLEN  16     // steps per chunk

template<int IQ>
__device__ __forceinline__ void scan_fold(
    const float (* __restrict__ dxs)[8],
    float (* __restrict__ sig3)[592],
    float* __restrict__ acc,
    int w, int lane, int j, int k,
    float* __restrict__ ob)
{
    constexpr int I0 = 2 * IQ;
    constexpr int I1 = 2 * IQ + 1;

    // ---------------- phase 2: one 16-step chunk per wave ----------------
    const int rbase = w * CLEN;
    float t1[8], t2r[8], t3r[8];          // full levels 1-3 (all 8 i)
    float s4v[2][8];
    #pragma unroll
    for (int i = 0; i < 8; ++i) { t1[i] = 0.f; t2r[i] = 0.f; t3r[i] = 0.f; }
    #pragma unroll
    for (int m = 0; m < 2; ++m)
        #pragma unroll
        for (int l = 0; l < 8; ++l) s4v[m][l] = 0.f;

    const float4* __restrict__ dx4 = reinterpret_cast<const float4*>(&dxs[0][0]);
    float own_p[2], bb_p[2];
    float4 r0_p[2], r1_p[2];
    #pragma unroll
    for (int u = 0; u < 2; ++u) {
        own_p[u] = dxs[rbase + u][k];
        bb_p[u]  = dxs[rbase + u][j];
        r0_p[u]  = dx4[2 * (rbase + u)];
        r1_p[u]  = dx4[2 * (rbase + u) + 1];
    }

    for (int tb = 0; tb < CLEN; tb += 2) {
        #pragma unroll
        for (int u = 0; u < 2; ++u) {
            const int tn = rbase + tb + u + 2;   // <= 257, zeroed slop
            float  own_n = dxs[tn][k];
            float  bb_n  = dxs[tn][j];
            float4 r0_n  = dx4[2 * tn];
            float4 r1_n  = dx4[2 * tn + 1];

            const float own = own_p[u];   // dx[k]
            const float bb  = bb_p[u];    // dx[j]
            const float4 r0 = r0_p[u];
            const float4 r1 = r1_p[u];
            const float rr[8] = { r0.x, r0.y, r0.z, r0.w, r1.x, r1.y, r1.z, r1.w };
            const float a0 = rr[I0];      // compile-time component
            const float a1 = rr[I1];

            // level-4 coefs straight from the table state (old values)
            const float c4_0 = fmaf(own, fmaf(bb, fmaf(t1[I0], (1.0f / 6.0f),
                                a0 * (1.0f / 24.0f)), 0.5f * t2r[I0]), t3r[I0]);
            const float c4_1 = fmaf(own, fmaf(bb, fmaf(t1[I1], (1.0f / 6.0f),
                                a1 * (1.0f / 24.0f)), 0.5f * t2r[I1]), t3r[I1]);
            #pragma unroll
            for (int l = 0; l < 8; ++l) {
                s4v[0][l] = fmaf(c4_0, rr[l], s4v[0][l]);
                s4v[1][l] = fmaf(c4_1, rr[l], s4v[1][l]);
            }
            // full level1-3 update (all 8 i) for the Chen table
            #pragma unroll
            for (int i = 0; i < 8; ++i) {
                const float a  = rr[i];
                const float c3 = fmaf(bb, fmaf(t1[i], 0.5f, a * (1.0f / 6.0f)), t2r[i]);
                t3r[i] = fmaf(c3, own, t3r[i]);
                t2r[i] = fmaf(fmaf(a, 0.5f, t1[i]), bb, t2r[i]);
                t1[i] += a;
            }

            own_p[u] = own_n; bb_p[u] = bb_n;
            r0_p[u] = r0_n;   r1_p[u] = r1_n;
        }
    }

    // chunk levels 1-3 -> table
    if (lane == 0) {
        #pragma unroll
        for (int i = 0; i < 8; ++i) sig3[w][i] = t1[i];
    }
    if (k == 0) {
        #pragma unroll
        for (int i = 0; i < 8; ++i) sig3[w][8 + i * 8 + j] = t2r[i];
    }
    #pragma unroll
    for (int i = 0; i < 8; ++i) sig3[w][72 + (i * 8 + j) * 8 + k] = t3r[i];
    __syncthreads();   // block-uniform path (switch on block-uniform iq)

    // ---------------- phase 3: Chen prefix + level-4 contribution --------
    float p1[2] = {0.f, 0.f}, p2[2] = {0.f, 0.f}, p3[2] = {0.f, 0.f};

    auto combine = [&](int cc) {
        const float* __restrict__ lp = sig3[cc];
        const float s1j  = lp[j];
        const float s1k  = lp[k];
        const float s2jk = lp[8 + j * 8 + k];
        #pragma unroll
        for (int m = 0; m < 2; ++m) {
            const int i = I0 + m;
            const float s1i  = lp[i];
            const float s2ij = lp[8 + i * 8 + j];
            const float s3i  = lp[72 + (i * 8 + j) * 8 + k];
            const float np3 = p3[m] + s3i + p1[m] * s2jk + p2[m] * s1k;
            const float np2 = p2[m] + s2ij + p1[m] * s1j;
            p3[m] = np3; p2[m] = np2; p1[m] += s1i;
        }
    };

    for (int cc = 0; cc < w; ++cc) combine(cc);   // prefix before own chunk
    {   // s4v += P (x) own-chunk lower levels
        const float* __restrict__ lp = sig3[w];
        const float4 s1a = *reinterpret_cast<const float4*>(lp);
        const float4 s1b = *reinterpret_cast<const float4*>(lp + 4);
        const float4 s2a = *reinterpret_cast<const float4*>(lp + 8 + k * 8);
        const float4 s2b = *reinterpret_cast<const float4*>(lp + 8 + k * 8 + 4);
        const float4 s3a = *reinterpret_cast<const float4*>(lp + 72 + (j * 8 + k) * 8);
        const float4 s3b = *reinterpret_cast<const float4*>(lp + 72 + (j * 8 + k) * 8 + 4);
        const float s1r[8] = { s1a.x, s1a.y, s1a.z, s1a.w, s1b.x, s1b.y, s1b.z, s1b.w };
        const float s2r[8] = { s2a.x, s2a.y, s2a.z, s2a.w, s2b.x, s2b.y, s2b.z, s2b.w };
        const float s3r[8] = { s3a.x, s3a.y, s3a.z, s3a.w, s3b.x, s3b.y, s3b.z, s3b.w };
        #pragma unroll
        for (int m = 0; m < 2; ++m)
            #pragma unroll
            for (int l = 0; l < 8; ++l)
                s4v[m][l] = fmaf(p1[m], s3r[l],
                             fmaf(p2[m], s2r[l],
                              fmaf(p3[m], s1r[l], s4v[m][l])));
    }

    if (w == NCH - 1) {
        combine(NCH - 1);   // full-path levels 1..3
        #pragma unroll
        for (int m = 0; m < 2; ++m) {
            const int i = I0 + m;
            if (lane == 0) ob[i] = p1[m];
            if (k == 0)    ob[8 + i * 8 + j] = p2[m];
            ob[72 + (i * 8 + j) * 8 + k] = p3[m];
        }
    }

    // ---------------- phase 4: conflict-free LDS atomic accumulate -------
    // acc[l*128 + m*64 + lane]: per instr lanes are stride-1 (2 lanes/bank, free)
    #pragma unroll
    for (int m = 0; m < 2; ++m)
        #pragma unroll
        for (int l = 0; l < 8; ++l)
            atomicAdd(&acc[l * 128 + m * 64 + lane], s4v[m][l]);
}

__global__ __launch_bounds__(1024) void sig_fused_kernel(
    const float* __restrict__ inp,
    const float* __restrict__ w1, const float* __restrict__ b1,
    const float* __restrict__ w2, const float* __restrict__ b2,
    const float* __restrict__ w3, const float* __restrict__ b3,
    float* __restrict__ out)
{
    const int blk  = blockIdx.x;      // 0..255
    const int b    = blk >> 2;        // batch
    const int iq   = blk & 3;         // i-pair
    const int tid  = threadIdx.x;     // 0..1023
    const int w    = tid >> 6;        // wave 0..15 = chunk id
    const int lane = tid & 63;
    const int j    = lane >> 3;
    const int k    = lane & 7;

    __shared__ __align__(16) float dxs[264][8];      // 256 steps + zero slop (8.25 KB)
    __shared__ __align__(16) float sig3[NCH][592];   // per-chunk s1|s2|s3 (37.9 KB)
    __shared__ __align__(16) float acc[1024];        // s4 accumulator (4 KB)

    // ---------------- phase 1: conv augment -> increments ----------------
    const float* __restrict__ x = inp + b * (L_IN * CIN);
    float o[8];
    if (tid < 253) {
        float h1[8];
        #pragma unroll
        for (int q = 0; q < 8; ++q) h1[q] = b1[q];
        #pragma unroll
        for (int kk = 0; kk < 4; ++kk) {
            #pragma unroll
            for (int ci = 0; ci < CIN; ++ci) {
                float v = x[(tid + kk) * CIN + ci];
                #pragma unroll
                for (int q = 0; q < 8; ++q) h1[q] = fmaf(v, w1[q * 20 + ci * 4 + kk], h1[q]);
            }
        }
        float r1v[8];
        #pragma unroll
        for (int q = 0; q < 8; ++q) r1v[q] = h1[q] > 0.f ? h1[q] : 0.f;
        float h2[8];
        #pragma unroll
        for (int q = 0; q < 8; ++q) h2[q] = b2[q];
        #pragma unroll
        for (int p = 0; p < 8; ++p) {
            #pragma unroll
            for (int q = 0; q < 8; ++q) h2[q] = fmaf(r1v[p], w2[q * 8 + p], h2[q]);
        }
        float r2v[8];
        #pragma unroll
        for (int q = 0; q < 8; ++q) r2v[q] = h2[q] > 0.f ? h2[q] : 0.f;
        float h30 = b3[0], h31 = b3[1];
        #pragma unroll
        for (int p = 0; p < 8; ++p) {
            h30 = fmaf(r2v[p], w3[p], h30);
            h31 = fmaf(r2v[p], w3[8 + p], h31);
        }
        #pragma unroll
        for (int cc = 0; cc < 5; ++cc) o[cc] = x[(tid + 3) * CIN + cc];
        o[5] = (float)(tid + 3) * (1.0f / 255.0f);
        o[6] = h30;
        o[7] = h31;
    }
    if (tid < 88) dxs[253 + (tid >> 3)][tid & 7] = 0.f;   // zero rows 253..263
    acc[tid] = 0.f;
    if (tid < 253) {
        #pragma unroll
        for (int ch = 0; ch < 8; ++ch) dxs[tid][ch] = o[ch];   // path rows
    }
    __syncthreads();
    float prevr[8];
    if (tid < 253) {
        #pragma unroll
        for (int ch = 0; ch < 8; ++ch) prevr[ch] = (tid > 0) ? dxs[tid - 1][ch] : 0.f;
    }
    __syncthreads();
    if (tid < 253) {
        #pragma unroll
        for (int ch = 0; ch < 8; ++ch) dxs[tid][ch] = o[ch] - prevr[ch];
    }
    __syncthreads();

    // ---------------- phases 2-4 (iq specialized, block-uniform switch) ---
    float* __restrict__ ob = out + (size_t)b * SIG_N;
    switch (iq) {
        case 0:  scan_fold<0>(dxs, sig3, acc, w, lane, j, k, ob); break;
        case 1:  scan_fold<1>(dxs, sig3, acc, w, lane, j, k, ob); break;
        case 2:  scan_fold<2>(dxs, sig3, acc, w, lane, j, k, ob); break;
        default: scan_fold<3>(dxs, sig3, acc, w, lane, j, k, ob); break;
    }
    __syncthreads();

    // ---------------- phase 5: coalesced s4 store ------------------------
    // out idx 584 + iq*1024 + tid, tid = m*512 + jk*8 + l; acc[l*128+m*64+jk]
    {
        const int l  = tid & 7;
        const int jk = (tid >> 3) & 63;
        const int m  = tid >> 9;
        ob[584 + iq * 1024 + tid] = acc[l * 128 + m * 64 + jk];
    }
}

extern "C" void kernel_launch(void* const* d_in, const int* in_sizes, int n_in,
                              void* d_out, int out_size, void* d_ws, size_t ws_size,
                              hipStream_t stream)
{
    const float* inp = (const float*)d_in[0];
    const float* w1  = (const float*)d_in[1];
    const float* b1  = (const float*)d_in[2];
    const float* w2  = (const float*)d_in[3];
    const float* b2  = (const float*)d_in[4];
    const float* w3  = (const float*)d_in[5];
    const float* b3  = (const float*)d_in[6];
    float* out = (float*)d_out;

    sig_fused_kernel<<<256, 1024, 0, stream>>>(inp, w1, b1, w2, b2, w3, b3, out);
}

// Round 10
// 88.805 us; speedup vs baseline: 4.4032x; 4.4032x over previous
//
#include <hip/hip_runtime.h>

// B=64, L=256, C_IN=5, KERNEL=4, C=8. 253 steps padded to 256 = 8 chunks x 32.
// ONE kernel, 256 blocks = (batch 64) x (i-pair 4), 512 thr = 8 waves
// (2 waves/SIMD). wave = chunk. Template-specialized on block-uniform iq
// (tracked i's compile-time -> no u-state, no selects). s4 reduction via
// conflict-free LDS atomicAdd (1 barrier, not 8).
// HARD CONSTRAINT (R5/R9 post-mortems): per-thread state needs >=128 VGPRs
// -> block size must stay <= 512 threads, code per instantiation small.
#define L_IN  256
#define CIN   5
#define SIG_N 4680   // 8 + 64 + 512 + 4096
#define NCH   8      // chunks
#define CLEN  32     // steps per chunk

template<int IQ>
__device__ __forceinline__ void scan_fold(
    const float (* __restrict__ dxs)[8],
    float (* __restrict__ sig3)[592],
    float* __restrict__ acc,
    int w, int lane, int j, int k,
    float* __restrict__ ob)
{
    constexpr int I0 = 2 * IQ;
    constexpr int I1 = 2 * IQ + 1;

    // ---------------- phase 2: one 32-step chunk per wave ----------------
    const int rbase = w * CLEN;
    float t1[8], t2r[8], t3r[8];          // full levels 1-3 (all 8 i)
    float s4v[2][8];
    #pragma unroll
    for (int i = 0; i < 8; ++i) { t1[i] = 0.f; t2r[i] = 0.f; t3r[i] = 0.f; }
    #pragma unroll
    for (int m = 0; m < 2; ++m)
        #pragma unroll
        for (int l = 0; l < 8; ++l) s4v[m][l] = 0.f;

    const float4* __restrict__ dx4 = reinterpret_cast<const float4*>(&dxs[0][0]);
    float own_p[2], bb_p[2];
    float4 r0_p[2], r1_p[2];
    #pragma unroll
    for (int u = 0; u < 2; ++u) {
        own_p[u] = dxs[rbase + u][k];
        bb_p[u]  = dxs[rbase + u][j];
        r0_p[u]  = dx4[2 * (rbase + u)];
        r1_p[u]  = dx4[2 * (rbase + u) + 1];
    }

    for (int tb = 0; tb < CLEN; tb += 2) {
        #pragma unroll
        for (int u = 0; u < 2; ++u) {
            const int tn = rbase + tb + u + 2;   // <= 257, zeroed slop
            float  own_n = dxs[tn][k];
            float  bb_n  = dxs[tn][j];
            float4 r0_n  = dx4[2 * tn];
            float4 r1_n  = dx4[2 * tn + 1];

            const float own = own_p[u];   // dx[k]
            const float bb  = bb_p[u];    // dx[j]
            const float4 r0 = r0_p[u];
            const float4 r1 = r1_p[u];
            const float rr[8] = { r0.x, r0.y, r0.z, r0.w, r1.x, r1.y, r1.z, r1.w };
            const float a0 = rr[I0];      // compile-time components
            const float a1 = rr[I1];

            // level-4 coefs straight from table state (old values)
            const float c4_0 = fmaf(own, fmaf(bb, fmaf(t1[I0], (1.0f / 6.0f),
                                a0 * (1.0f / 24.0f)), 0.5f * t2r[I0]), t3r[I0]);
            const float c4_1 = fmaf(own, fmaf(bb, fmaf(t1[I1], (1.0f / 6.0f),
                                a1 * (1.0f / 24.0f)), 0.5f * t2r[I1]), t3r[I1]);
            #pragma unroll
            for (int l = 0; l < 8; ++l) {
                s4v[0][l] = fmaf(c4_0, rr[l], s4v[0][l]);
                s4v[1][l] = fmaf(c4_1, rr[l], s4v[1][l]);
            }
            // full level1-3 update (all 8 i) for the Chen table
            #pragma unroll
            for (int i = 0; i < 8; ++i) {
                const float a  = rr[i];
                const float c3 = fmaf(bb, fmaf(t1[i], 0.5f, a * (1.0f / 6.0f)), t2r[i]);
                t3r[i] = fmaf(c3, own, t3r[i]);
                t2r[i] = fmaf(fmaf(a, 0.5f, t1[i]), bb, t2r[i]);
                t1[i] += a;
            }

            own_p[u] = own_n; bb_p[u] = bb_n;
            r0_p[u] = r0_n;   r1_p[u] = r1_n;
        }
    }

    // chunk levels 1-3 -> table
    if (lane == 0) {
        #pragma unroll
        for (int i = 0; i < 8; ++i) sig3[w][i] = t1[i];
    }
    if (k == 0) {
        #pragma unroll
        for (int i = 0; i < 8; ++i) sig3[w][8 + i * 8 + j] = t2r[i];
    }
    #pragma unroll
    for (int i = 0; i < 8; ++i) sig3[w][72 + (i * 8 + j) * 8 + k] = t3r[i];
    __syncthreads();   // safe: switch is on block-uniform iq

    // ---------------- phase 3: Chen prefix + level-4 contribution --------
    float p1[2] = {0.f, 0.f}, p2[2] = {0.f, 0.f}, p3[2] = {0.f, 0.f};

    auto combine = [&](int cc) {
        const float* __restrict__ lp = sig3[cc];
        const float s1j  = lp[j];
        const float s1k  = lp[k];
        const float s2jk = lp[8 + j * 8 + k];
        #pragma unroll
        for (int m = 0; m < 2; ++m) {
            const int i = I0 + m;
            const float s1i  = lp[i];
            const float s2ij = lp[8 + i * 8 + j];
            const float s3i  = lp[72 + (i * 8 + j) * 8 + k];
            const float np3 = p3[m] + s3i + p1[m] * s2jk + p2[m] * s1k;
            const float np2 = p2[m] + s2ij + p1[m] * s1j;
            p3[m] = np3; p2[m] = np2; p1[m] += s1i;
        }
    };

    for (int cc = 0; cc < w; ++cc) combine(cc);   // prefix before own chunk
    {   // s4v += P (x) own-chunk lower levels
        const float* __restrict__ lp = sig3[w];
        const float4 s1a = *reinterpret_cast<const float4*>(lp);
        const float4 s1b = *reinterpret_cast<const float4*>(lp + 4);
        const float4 s2a = *reinterpret_cast<const float4*>(lp + 8 + k * 8);
        const float4 s2b = *reinterpret_cast<const float4*>(lp + 8 + k * 8 + 4);
        const float4 s3a = *reinterpret_cast<const float4*>(lp + 72 + (j * 8 + k) * 8);
        const float4 s3b = *reinterpret_cast<const float4*>(lp + 72 + (j * 8 + k) * 8 + 4);
        const float s1r[8] = { s1a.x, s1a.y, s1a.z, s1a.w, s1b.x, s1b.y, s1b.z, s1b.w };
        const float s2r[8] = { s2a.x, s2a.y, s2a.z, s2a.w, s2b.x, s2b.y, s2b.z, s2b.w };
        const float s3r[8] = { s3a.x, s3a.y, s3a.z, s3a.w, s3b.x, s3b.y, s3b.z, s3b.w };
        #pragma unroll
        for (int m = 0; m < 2; ++m)
            #pragma unroll
            for (int l = 0; l < 8; ++l)
                s4v[m][l] = fmaf(p1[m], s3r[l],
                             fmaf(p2[m], s2r[l],
                              fmaf(p3[m], s1r[l], s4v[m][l])));
    }

    if (w == NCH - 1) {
        combine(NCH - 1);   // full-path levels 1..3
        #pragma unroll
        for (int m = 0; m < 2; ++m) {
            const int i = I0 + m;
            if (lane == 0) ob[i] = p1[m];
            if (k == 0)    ob[8 + i * 8 + j] = p2[m];
            ob[72 + (i * 8 + j) * 8 + k] = p3[m];
        }
    }

    // ---------------- phase 4: conflict-free LDS atomic accumulate -------
    // acc[l*128 + m*64 + lane]: lanes stride-1 per instr (2 lanes/bank, free)
    #pragma unroll
    for (int m = 0; m < 2; ++m)
        #pragma unroll
        for (int l = 0; l < 8; ++l)
            atomicAdd(&acc[l * 128 + m * 64 + lane], s4v[m][l]);
}

__global__ __launch_bounds__(512) void sig_fused_kernel(
    const float* __restrict__ inp,
    const float* __restrict__ w1, const float* __restrict__ b1,
    const float* __restrict__ w2, const float* __restrict__ b2,
    const float* __restrict__ w3, const float* __restrict__ b3,
    float* __restrict__ out)
{
    const int blk  = blockIdx.x;      // 0..255
    const int b    = blk >> 2;        // batch
    const int iq   = blk & 3;         // i-pair
    const int tid  = threadIdx.x;     // 0..511
    const int w    = tid >> 6;        // wave 0..7 = chunk id
    const int lane = tid & 63;
    const int j    = lane >> 3;
    const int k    = lane & 7;

    __shared__ __align__(16) float pbuf[253][8];     // augmented path rows
    __shared__ __align__(16) float dxs[264][8];      // 256 increments + slop
    __shared__ __align__(16) float sig3[NCH][592];   // per-chunk s1|s2|s3
    __shared__ __align__(16) float acc[1024];        // s4 accumulator

    // ---------------- phase 1: conv augment -> increments ----------------
    const float* __restrict__ x = inp + b * (L_IN * CIN);
    if (tid < 253) {
        float h1[8];
        #pragma unroll
        for (int q = 0; q < 8; ++q) h1[q] = b1[q];
        #pragma unroll
        for (int kk = 0; kk < 4; ++kk) {
            #pragma unroll
            for (int ci = 0; ci < CIN; ++ci) {
                float v = x[(tid + kk) * CIN + ci];
                #pragma unroll
                for (int q = 0; q < 8; ++q) h1[q] = fmaf(v, w1[q * 20 + ci * 4 + kk], h1[q]);
            }
        }
        float r1v[8];
        #pragma unroll
        for (int q = 0; q < 8; ++q) r1v[q] = h1[q] > 0.f ? h1[q] : 0.f;
        float h2[8];
        #pragma unroll
        for (int q = 0; q < 8; ++q) h2[q] = b2[q];
        #pragma unroll
        for (int p = 0; p < 8; ++p) {
            #pragma unroll
            for (int q = 0; q < 8; ++q) h2[q] = fmaf(r1v[p], w2[q * 8 + p], h2[q]);
        }
        float r2v[8];
        #pragma unroll
        for (int q = 0; q < 8; ++q) r2v[q] = h2[q] > 0.f ? h2[q] : 0.f;
        float h30 = b3[0], h31 = b3[1];
        #pragma unroll
        for (int p = 0; p < 8; ++p) {
            h30 = fmaf(r2v[p], w3[p], h30);
            h31 = fmaf(r2v[p], w3[8 + p], h31);
        }
        pbuf[tid][0] = x[(tid + 3) * CIN + 0];
        pbuf[tid][1] = x[(tid + 3) * CIN + 1];
        pbuf[tid][2] = x[(tid + 3) * CIN + 2];
        pbuf[tid][3] = x[(tid + 3) * CIN + 3];
        pbuf[tid][4] = x[(tid + 3) * CIN + 4];
        pbuf[tid][5] = (float)(tid + 3) * (1.0f / 255.0f);
        pbuf[tid][6] = h30;
        pbuf[tid][7] = h31;
    }
    if (tid < 88) dxs[253 + (tid >> 3)][tid & 7] = 0.f;   // zero rows 253..263
    acc[tid] = 0.f; acc[tid + 512] = 0.f;
    __syncthreads();
    if (tid < 253) {
        #pragma unroll
        for (int ch = 0; ch < 8; ++ch) {
            const float prev = (tid > 0) ? pbuf[tid - 1][ch] : 0.f;
            dxs[tid][ch] = pbuf[tid][ch] - prev;
        }
    }
    __syncthreads();

    // ---------------- phases 2-4 (iq specialized, block-uniform switch) ---
    float* __restrict__ ob = out + (size_t)b * SIG_N;
    switch (iq) {
        case 0:  scan_fold<0>(dxs, sig3, acc, w, lane, j, k, ob); break;
        case 1:  scan_fold<1>(dxs, sig3, acc, w, lane, j, k, ob); break;
        case 2:  scan_fold<2>(dxs, sig3, acc, w, lane, j, k, ob); break;
        default: scan_fold<3>(dxs, sig3, acc, w, lane, j, k, ob); break;
    }
    __syncthreads();

    // ---------------- phase 5: coalesced s4 store ------------------------
    // out idx 584 + iq*1024 + (m*512 + jk*8 + l); acc[l*128 + m*64 + jk]
    #pragma unroll
    for (int h = 0; h < 2; ++h) {
        const int idx = h * 512 + tid;          // 0..1023
        const int l   = idx & 7;
        const int jk  = (idx >> 3) & 63;
        const int m   = idx >> 9;
        ob[584 + iq * 1024 + idx] = acc[l * 128 + m * 64 + jk];
    }
}

extern "C" void kernel_launch(void* const* d_in, const int* in_sizes, int n_in,
                              void* d_out, int out_size, void* d_ws, size_t ws_size,
                              hipStream_t stream)
{
    const float* inp = (const float*)d_in[0];
    const float* w1  = (const float*)d_in[1];
    const float* b1  = (const float*)d_in[2];
    const float* w2  = (const float*)d_in[3];
    const float* b2  = (const float*)d_in[4];
    const float* w3  = (const float*)d_in[5];
    const float* b3  = (const float*)d_in[6];
    float* out = (float*)d_out;

    sig_fused_kernel<<<256, 512, 0, stream>>>(inp, w1, b1, w2, b2, w3, b3, out);
}

// Round 11
// 80.577 us; speedup vs baseline: 4.8528x; 1.1021x over previous
//
#include <hip/hip_runtime.h>

// B=64, L=256, C_IN=5, KERNEL=4, C=8. 253 steps padded to 256 = 8 chunks x 32.
// ONE kernel, 256 blocks = (batch 64) x (i-pair 4), 512 thr = 8 waves.
// wave = chunk (32 serial iters) and 2 waves/SIMD device-wide.
// Wave scans its chunk tracking FULL levels 1-3 (all 8 i, for the Chen table)
// + level-4 rows for the block's two i's. Chen fold is all in-LDS.
// === R8 VERBATIM (measured best: 81.4 us). R9 (1024thr: VGPR cap 64 ->
// 912 MB scratch spill, 391 us) and R10 (iq-templates + ds_add: +7.4 us)
// both regressed; per theory-first discipline, unmatched predictions are
// not committed. Hard constraints learned: per-thread state needs >=128
// VGPRs (block <= 512 thr); no N-way inlined specialization of the scan.
#define L_IN  256
#define CIN   5
#define SIG_N 4680   // 8 + 64 + 512 + 4096

__global__ __launch_bounds__(512) void sig_fused_kernel(
    const float* __restrict__ inp,
    const float* __restrict__ w1, const float* __restrict__ b1,
    const float* __restrict__ w2, const float* __restrict__ b2,
    const float* __restrict__ w3, const float* __restrict__ b3,
    float* __restrict__ out)
{
    const int blk  = blockIdx.x;      // 0..255
    const int b    = blk >> 2;        // batch
    const int iq   = blk & 3;         // i0=2iq, i1=2iq+1
    const int tid  = threadIdx.x;     // 0..511
    const int w    = tid >> 6;        // wave 0..7 = chunk id
    const int lane = tid & 63;
    const int j    = lane >> 3;
    const int k    = lane & 7;

    __shared__ __align__(16) float dxs[264][8];    // 256 steps + zero slop
    __shared__ __align__(16) float sig3[8][592];   // per-chunk s1|s2|s3 (584 used)
    __shared__ __align__(16) float acc[1024];      // s4 accum [m][jk][l]
    __shared__ float pad_lds[8192];                // occupancy cap: <=2 blocks/CU

    // keep pad_lds allocated (never executes; grid size opaque to compiler)
    if (blk & 0x40000000) out[0] = pad_lds[tid];

    // ---------------- phase 1: conv augment -> increments ----------------
    const float* __restrict__ x = inp + b * (L_IN * CIN);
    float o[8];
    if (tid < 253) {
        float h1[8];
        #pragma unroll
        for (int q = 0; q < 8; ++q) h1[q] = b1[q];
        #pragma unroll
        for (int kk = 0; kk < 4; ++kk) {
            #pragma unroll
            for (int ci = 0; ci < CIN; ++ci) {
                float v = x[(tid + kk) * CIN + ci];
                #pragma unroll
                for (int q = 0; q < 8; ++q) h1[q] = fmaf(v, w1[q * 20 + ci * 4 + kk], h1[q]);
            }
        }
        float r1v[8];
        #pragma unroll
        for (int q = 0; q < 8; ++q) r1v[q] = h1[q] > 0.f ? h1[q] : 0.f;
        float h2[8];
        #pragma unroll
        for (int q = 0; q < 8; ++q) h2[q] = b2[q];
        #pragma unroll
        for (int p = 0; p < 8; ++p) {
            #pragma unroll
            for (int q = 0; q < 8; ++q) h2[q] = fmaf(r1v[p], w2[q * 8 + p], h2[q]);
        }
        float r2v[8];
        #pragma unroll
        for (int q = 0; q < 8; ++q) r2v[q] = h2[q] > 0.f ? h2[q] : 0.f;
        float h30 = b3[0], h31 = b3[1];
        #pragma unroll
        for (int p = 0; p < 8; ++p) {
            h30 = fmaf(r2v[p], w3[p], h30);
            h31 = fmaf(r2v[p], w3[8 + p], h31);
        }
        #pragma unroll
        for (int cc = 0; cc < 5; ++cc) o[cc] = x[(tid + 3) * CIN + cc];
        o[5] = (float)(tid + 3) * (1.0f / 255.0f);
        o[6] = h30;
        o[7] = h31;
    }
    if (tid < 88) dxs[253 + (tid >> 3)][tid & 7] = 0.f;   // zero rows 253..263
    acc[tid] = 0.f; acc[tid + 512] = 0.f;
    if (tid < 253) {
        #pragma unroll
        for (int ch = 0; ch < 8; ++ch) dxs[tid][ch] = o[ch];   // path rows
    }
    __syncthreads();
    float prevr[8];
    if (tid < 253) {
        #pragma unroll
        for (int ch = 0; ch < 8; ++ch) prevr[ch] = (tid > 0) ? dxs[tid - 1][ch] : 0.f;
    }
    __syncthreads();
    if (tid < 253) {
        #pragma unroll
        for (int ch = 0; ch < 8; ++ch) dxs[tid][ch] = o[ch] - prevr[ch];
    }
    __syncthreads();

    // ---------------- phase 2: one 32-step chunk per wave ----------------
    const int rbase = w * 32;
    float t1[8], t2r[8], t3r[8];          // full level1-3 (all 8 i) for table
    float u1[2] = {0.f, 0.f}, u2[2] = {0.f, 0.f}, u3[2] = {0.f, 0.f};
    float s4v[2][8];
    #pragma unroll
    for (int i = 0; i < 8; ++i) { t1[i] = 0.f; t2r[i] = 0.f; t3r[i] = 0.f; }
    #pragma unroll
    for (int m = 0; m < 2; ++m)
        #pragma unroll
        for (int l = 0; l < 8; ++l) s4v[m][l] = 0.f;

    const float4* __restrict__ dx4 = reinterpret_cast<const float4*>(&dxs[0][0]);
    float own_p[2], bb_p[2];
    float4 r0_p[2], r1_p[2];
    #pragma unroll
    for (int u = 0; u < 2; ++u) {
        own_p[u] = dxs[rbase + u][k];
        bb_p[u]  = dxs[rbase + u][j];
        r0_p[u]  = dx4[2 * (rbase + u)];
        r1_p[u]  = dx4[2 * (rbase + u) + 1];
    }

    for (int tb = 0; tb < 32; tb += 2) {
        #pragma unroll
        for (int u = 0; u < 2; ++u) {
            const int tn = rbase + tb + u + 2;   // <= 257, zeroed slop
            float  own_n = dxs[tn][k];
            float  bb_n  = dxs[tn][j];
            float4 r0_n  = dx4[2 * tn];
            float4 r1_n  = dx4[2 * tn + 1];

            const float own = own_p[u];   // dx[k]
            const float bb  = bb_p[u];    // dx[j]
            const float4 r0 = r0_p[u];
            const float4 r1 = r1_p[u];
            const float rr[8] = { r0.x, r0.y, r0.z, r0.w, r1.x, r1.y, r1.z, r1.w };
            const float a0 = (iq == 0) ? r0.x : (iq == 1) ? r0.z
                           : (iq == 2) ? r1.x : r1.z;
            const float a1 = (iq == 0) ? r0.y : (iq == 1) ? r0.w
                           : (iq == 2) ? r1.y : r1.w;

            // level-4 for the block's two i's (u-state is their private copy)
            const float c4_0 = fmaf(own, fmaf(bb, fmaf(u1[0], (1.0f / 6.0f),
                                a0 * (1.0f / 24.0f)), 0.5f * u2[0]), u3[0]);
            const float c4_1 = fmaf(own, fmaf(bb, fmaf(u1[1], (1.0f / 6.0f),
                                a1 * (1.0f / 24.0f)), 0.5f * u2[1]), u3[1]);
            #pragma unroll
            for (int l = 0; l < 8; ++l) {
                s4v[0][l] = fmaf(c4_0, rr[l], s4v[0][l]);
                s4v[1][l] = fmaf(c4_1, rr[l], s4v[1][l]);
            }
            u3[0] = fmaf(fmaf(bb, fmaf(u1[0], 0.5f, a0 * (1.0f / 6.0f)), u2[0]), own, u3[0]);
            u2[0] = fmaf(fmaf(a0, 0.5f, u1[0]), bb, u2[0]);
            u1[0] += a0;
            u3[1] = fmaf(fmaf(bb, fmaf(u1[1], 0.5f, a1 * (1.0f / 6.0f)), u2[1]), own, u3[1]);
            u2[1] = fmaf(fmaf(a1, 0.5f, u1[1]), bb, u2[1]);
            u1[1] += a1;

            // full level1-3 update for the Chen table
            #pragma unroll
            for (int i = 0; i < 8; ++i) {
                const float a  = rr[i];
                const float c3 = fmaf(bb, fmaf(t1[i], 0.5f, a * (1.0f / 6.0f)), t2r[i]);
                t3r[i] = fmaf(c3, own, t3r[i]);
                t2r[i] = fmaf(fmaf(a, 0.5f, t1[i]), bb, t2r[i]);
                t1[i] += a;
            }

            own_p[u] = own_n; bb_p[u] = bb_n;
            r0_p[u] = r0_n;   r1_p[u] = r1_n;
        }
    }

    // chunk level1-3 -> table
    if (lane == 0) {
        #pragma unroll
        for (int i = 0; i < 8; ++i) sig3[w][i] = t1[i];
    }
    if (k == 0) {
        #pragma unroll
        for (int i = 0; i < 8; ++i) sig3[w][8 + i * 8 + j] = t2r[i];
    }
    #pragma unroll
    for (int i = 0; i < 8; ++i) sig3[w][72 + (i * 8 + j) * 8 + k] = t3r[i];
    __syncthreads();

    // ---------------- phase 3: Chen prefix + level-4 contribution ---------
    const int i0 = 2 * iq;
    float p1[2] = {0.f, 0.f}, p2[2] = {0.f, 0.f}, p3[2] = {0.f, 0.f};

    auto combine = [&](int cc) {
        const float* __restrict__ lp = sig3[cc];
        const float s1j  = lp[j];
        const float s1k  = lp[k];
        const float s2jk = lp[8 + j * 8 + k];
        #pragma unroll
        for (int m = 0; m < 2; ++m) {
            const int i = i0 + m;
            const float s1i  = lp[i];
            const float s2ij = lp[8 + i * 8 + j];
            const float s3i  = lp[72 + (i * 8 + j) * 8 + k];
            const float np3 = p3[m] + s3i + p1[m] * s2jk + p2[m] * s1k;
            const float np2 = p2[m] + s2ij + p1[m] * s1j;
            p3[m] = np3; p2[m] = np2; p1[m] += s1i;
        }
    };

    for (int cc = 0; cc < w; ++cc) combine(cc);   // prefix before own chunk
    {   // s4v += P (x) own-chunk lower levels
        const float* __restrict__ lp = sig3[w];
        const float4 s1a = *reinterpret_cast<const float4*>(lp);
        const float4 s1b = *reinterpret_cast<const float4*>(lp + 4);
        const float4 s2a = *reinterpret_cast<const float4*>(lp + 8 + k * 8);
        const float4 s2b = *reinterpret_cast<const float4*>(lp + 8 + k * 8 + 4);
        const float4 s3a = *reinterpret_cast<const float4*>(lp + 72 + (j * 8 + k) * 8);
        const float4 s3b = *reinterpret_cast<const float4*>(lp + 72 + (j * 8 + k) * 8 + 4);
        const float s1r[8] = { s1a.x, s1a.y, s1a.z, s1a.w, s1b.x, s1b.y, s1b.z, s1b.w };
        const float s2r[8] = { s2a.x, s2a.y, s2a.z, s2a.w, s2b.x, s2b.y, s2b.z, s2b.w };
        const float s3r[8] = { s3a.x, s3a.y, s3a.z, s3a.w, s3b.x, s3b.y, s3b.z, s3b.w };
        #pragma unroll
        for (int m = 0; m < 2; ++m)
            #pragma unroll
            for (int l = 0; l < 8; ++l)
                s4v[m][l] = fmaf(p1[m], s3r[l],
                             fmaf(p2[m], s2r[l],
                              fmaf(p3[m], s1r[l], s4v[m][l])));
    }

    float* __restrict__ ob = out + (size_t)b * SIG_N;
    if (w == 7) {
        combine(7);   // full-path levels 1..3
        #pragma unroll
        for (int m = 0; m < 2; ++m) {
            const int i = i0 + m;
            if (lane == 0) ob[i] = p1[m];
            if (k == 0)    ob[8 + i * 8 + j] = p2[m];
            ob[72 + (i * 8 + j) * 8 + k] = p3[m];
        }
    }

    // ---------------- phase 4: accumulate s4 across the 8 waves ----------
    #pragma unroll
    for (int ph = 0; ph < 8; ++ph) {
        if (w == ph) {
            #pragma unroll
            for (int m = 0; m < 2; ++m) {
                float4* ap = reinterpret_cast<float4*>(&acc[m * 512 + lane * 8]);
                float4 v0 = ap[0], v1 = ap[1];
                v0.x += s4v[m][0]; v0.y += s4v[m][1]; v0.z += s4v[m][2]; v0.w += s4v[m][3];
                v1.x += s4v[m][4]; v1.y += s4v[m][5]; v1.z += s4v[m][6]; v1.w += s4v[m][7];
                ap[0] = v0; ap[1] = v1;
            }
        }
        __syncthreads();
    }

    // ---------------- phase 5: coalesced s4 store ------------------------
    // local index 2*tid decomposes as m*512 + (j*8+k)*8 + l  == global layout
    float2 v = *reinterpret_cast<float2*>(&acc[2 * tid]);
    *reinterpret_cast<float2*>(ob + 584 + iq * 1024 + 2 * tid) = v;
}

extern "C" void kernel_launch(void* const* d_in, const int* in_sizes, int n_in,
                              void* d_out, int out_size, void* d_ws, size_t ws_size,
                              hipStream_t stream)
{
    const float* inp = (const float*)d_in[0];
    const float* w1  = (const float*)d_in[1];
    const float* b1  = (const float*)d_in[2];
    const float* w2  = (const float*)d_in[3];
    const float* b2  = (const float*)d_in[4];
    const float* w3  = (const float*)d_in[5];
    const float* b3  = (const float*)d_in[6];
    float* out = (float*)d_out;

    sig_fused_kernel<<<256, 512, 0, stream>>>(inp, w1, b1, w2, b2, w3, b3, out);
}